// Round 5
// baseline (1108.645 us; speedup 1.0000x reference)
//
#include <hip/hip_runtime.h>
#include <cmath>
#include <cstdint>
#include <cstddef>

#define BB 8
#define EE 1024
#define SS 2000
#define HH 16
#define HDIM 64
#define MLM 10
#define MLPD 4096
#define QKV_N 3072
#define QK_SCALE 0.35355339059327373f

typedef __attribute__((ext_vector_type(8))) short short8v;
typedef __attribute__((ext_vector_type(4))) float f32x4;

static __device__ __forceinline__ short f2bf(float x) {
  unsigned u = __builtin_bit_cast(unsigned, x);
  unsigned r = (u + 0x7fffu + ((u >> 16) & 1u)) >> 16;
  return (short)(unsigned short)r;
}
static __device__ __forceinline__ float bf2f(short x) {
  unsigned u = ((unsigned)(unsigned short)x) << 16;
  return __builtin_bit_cast(float, u);
}

// ---------------- X (B,E,S) f32 -> xb (B,S,E) bf16 ----------------
__global__ __launch_bounds__(256) void transpose_x(const float* __restrict__ X, short* __restrict__ xb) {
  __shared__ float tile[32][33];
  int b = blockIdx.z;
  int e0 = blockIdx.y * 32;
  int s0 = blockIdx.x * 32;
  int tx = threadIdx.x;      // 0..31
  int ty = threadIdx.y;      // 0..7
#pragma unroll
  for (int i = 0; i < 32; i += 8) {
    int e = e0 + ty + i, s = s0 + tx;
    tile[ty + i][tx] = (s < SS) ? X[((size_t)b * EE + e) * SS + s] : 0.f;
  }
  __syncthreads();
#pragma unroll
  for (int i = 0; i < 32; i += 8) {
    int s = s0 + ty + i, e = e0 + tx;
    if (s < SS) xb[((size_t)b * SS + s) * EE + e] = f2bf(tile[tx][ty + i]);
  }
}

// ---------------- f32 -> bf16 cast ----------------
__global__ __launch_bounds__(256) void cast_f2b(const float* __restrict__ src, short* __restrict__ dst, int n) {
  int i = blockIdx.x * 256 + threadIdx.x;
  int stride = gridDim.x * 256;
  for (; i < n; i += stride) dst[i] = f2bf(src[i]);
}

// ---------------- bf16 MFMA GEMM: C[m,n] = sum_k A[m,k]*Bm[n,k] ----------------
// mode 0: QKV  ((acc+bias)*scale for n<2048), bf16 out, N=3072
// mode 1: MLP1 (acc+bias then exact GELU), bf16 out
// mode 2: MLP2 (acc+bias), f32 out
__global__ __launch_bounds__(256) void gemm_bt(
    const short* __restrict__ A, const short* __restrict__ Bm, void* __restrict__ Cv,
    int K, int N, int mode,
    const float* __restrict__ p0, const float* __restrict__ p1, const float* __restrict__ p2)
{
  __shared__ __align__(16) short As[128 * 32];
  __shared__ __align__(16) short Bs[128 * 32];
  int tid = threadIdx.x;
  int m0 = blockIdx.x * 128, n0 = blockIdx.y * 128;
  int wave = tid >> 6, lane = tid & 63;
  int wm = (wave & 1) * 64, wn = (wave >> 1) * 64;
  int lm = lane & 15, quad = lane >> 4;
  int sr = tid >> 2;          // 0..63
  int sc = (tid & 3) << 3;    // 0,8,16,24
  const short* Abase = A + (size_t)(m0 + sr) * K + sc;
  const short* Bbase = Bm + (size_t)(n0 + sr) * K + sc;
  f32x4 acc[4][4];
#pragma unroll
  for (int i = 0; i < 4; i++)
#pragma unroll
    for (int j = 0; j < 4; j++) acc[i][j] = (f32x4){0.f, 0.f, 0.f, 0.f};

  for (int k0 = 0; k0 < K; k0 += 32) {
    __syncthreads();
    *(short8v*)&As[sr * 32 + sc]        = *(const short8v*)(Abase + k0);
    *(short8v*)&As[(sr + 64) * 32 + sc] = *(const short8v*)(Abase + (size_t)64 * K + k0);
    *(short8v*)&Bs[sr * 32 + sc]        = *(const short8v*)(Bbase + k0);
    *(short8v*)&Bs[(sr + 64) * 32 + sc] = *(const short8v*)(Bbase + (size_t)64 * K + k0);
    __syncthreads();
    short8v af[4], bfr[4];
#pragma unroll
    for (int i = 0; i < 4; i++) af[i] = *(const short8v*)&As[(wm + i * 16 + lm) * 32 + quad * 8];
#pragma unroll
    for (int j = 0; j < 4; j++) bfr[j] = *(const short8v*)&Bs[(wn + j * 16 + lm) * 32 + quad * 8];
#pragma unroll
    for (int i = 0; i < 4; i++)
#pragma unroll
      for (int j = 0; j < 4; j++)
        acc[i][j] = __builtin_amdgcn_mfma_f32_16x16x32_bf16(af[i], bfr[j], acc[i][j], 0, 0, 0);
  }
#pragma unroll
  for (int i = 0; i < 4; i++) {
#pragma unroll
    for (int j = 0; j < 4; j++) {
      int col = n0 + wn + j * 16 + lm;
      float bias, scl = 1.f;
      if (mode == 0) {
        if (col < 1024)      { bias = p0[col];        scl = QK_SCALE; }
        else if (col < 2048) { bias = p1[col - 1024]; scl = QK_SCALE; }
        else                 { bias = p2[col - 2048]; }
      } else {
        bias = p0[col];
      }
#pragma unroll
      for (int r = 0; r < 4; r++) {
        int row = m0 + wm + i * 16 + quad * 4 + r;
        float v = acc[i][j][r] + bias;
        if (mode == 0)      v *= scl;
        else if (mode == 1) v = 0.5f * v * (1.f + erff(v * 0.70710678118f));
        if (mode == 2) ((float*)Cv)[(size_t)row * N + col] = v;
        else           ((short*)Cv)[(size_t)row * N + col] = f2bf(v);
      }
    }
  }
}

// ---------------- landmarks: mean over 200-row segments ----------------
__global__ __launch_bounds__(64) void landmarks(const short* __restrict__ QKV, float* __restrict__ Ql, float* __restrict__ Kl) {
  int d = threadIdx.x;
  int bhm = blockIdx.x;
  int part = blockIdx.y;
  int b = bhm / (HH * MLM);
  int h = (bhm / MLM) % HH;
  int m = bhm % MLM;
  const short* src = QKV + (part ? 1024 : 0);
  size_t base = ((size_t)(b * SS + m * 200)) * QKV_N + h * HDIM + d;
  float acc = 0.f;
  for (int i = 0; i < 200; i++) acc += bf2f(src[base + (size_t)i * QKV_N]);
  float* dst = part ? Kl : Ql;
  dst[((size_t)(b * HH + h) * MLM + m) * HDIM + d] = acc * (1.f / 200.f);
}

// ---------------- k2 = softmax(Ql Kl^T) + per-bh col-sum/row-sum maxima ----------------
__global__ __launch_bounds__(128) void k2stats(const float* __restrict__ Ql, const float* __restrict__ Kl,
                                               float* __restrict__ k2, float* __restrict__ cmax, float* __restrict__ rmax) {
  int bh = blockIdx.x;
  __shared__ float QlS[640], KlS[640], zz[100], k2s[100], cs[10], rs[10];
  for (int i = threadIdx.x; i < 640; i += 128) {
    QlS[i] = Ql[(size_t)bh * 640 + i];
    KlS[i] = Kl[(size_t)bh * 640 + i];
  }
  __syncthreads();
  if (threadIdx.x < 100) {
    int i = threadIdx.x / 10, j = threadIdx.x % 10;
    float z = 0.f;
    for (int d = 0; d < 64; d++) z += QlS[i * 64 + d] * KlS[j * 64 + d];
    zz[threadIdx.x] = z;
  }
  __syncthreads();
  if (threadIdx.x < 10) {
    int i = threadIdx.x;
    float mx = -1e30f;
    for (int j = 0; j < 10; j++) mx = fmaxf(mx, zz[i * 10 + j]);
    float s = 0.f, e[10];
    for (int j = 0; j < 10; j++) { e[j] = expf(zz[i * 10 + j] - mx); s += e[j]; }
    float inv = 1.f / s, rsum = 0.f;
    for (int j = 0; j < 10; j++) {
      float v = e[j] * inv;
      k2s[i * 10 + j] = v;
      k2[(size_t)bh * 100 + i * 10 + j] = v;
      rsum += v;
    }
    rs[i] = rsum;
  }
  __syncthreads();
  if (threadIdx.x < 10) {
    int j = threadIdx.x;
    float c = 0.f;
    for (int i = 0; i < 10; i++) c += k2s[i * 10 + j];
    cs[j] = c;
  }
  __syncthreads();
  if (threadIdx.x == 0) {
    float m1 = 0.f, m2 = 0.f;
    for (int j = 0; j < 10; j++) { m1 = fmaxf(m1, cs[j]); m2 = fmaxf(m2, rs[j]); }
    cmax[bh] = m1;
    rmax[bh] = m2;
  }
}

// ---------------- Newton-Schulz pseudo-inverse of k2 (10x10), 6 iters ----------------
__global__ __launch_bounds__(128) void invk(const float* __restrict__ k2, const float* __restrict__ cmax,
                                            const float* __restrict__ rmax, float* __restrict__ invo) {
  int bh = blockIdx.x;
  __shared__ float gsc;
  __shared__ float Km[100], Vm[100], KV[100], Ta[100], Tb[100];
  if (threadIdx.x == 0) {
    float mc = 0.f, mr = 0.f;
    for (int i = 0; i < 128; i++) { mc = fmaxf(mc, cmax[i]); mr = fmaxf(mr, rmax[i]); }
    gsc = 1.f / (mc * mr);
  }
  for (int i = threadIdx.x; i < 100; i += 128) Km[i] = k2[(size_t)bh * 100 + i];
  __syncthreads();
  int t = threadIdx.x;
  int i = t / 10, j = t % 10;
  bool act = t < 100;
  if (act) Vm[t] = Km[j * 10 + i] * gsc;
  __syncthreads();
  for (int it = 0; it < 6; it++) {
    if (act) { float a = 0.f; for (int k = 0; k < 10; k++) a += Km[i * 10 + k] * Vm[k * 10 + j]; KV[t] = a; }
    __syncthreads();
    if (act) Ta[t] = (i == j ? 7.f : 0.f) - KV[t];
    __syncthreads();
    if (act) { float a = 0.f; for (int k = 0; k < 10; k++) a += KV[i * 10 + k] * Ta[k * 10 + j]; Tb[t] = (i == j ? 15.f : 0.f) - a; }
    __syncthreads();
    if (act) { float a = 0.f; for (int k = 0; k < 10; k++) a += KV[i * 10 + k] * Tb[k * 10 + j]; Ta[t] = (i == j ? 13.f : 0.f) - a; }
    __syncthreads();
    if (act) { float a = 0.f; for (int k = 0; k < 10; k++) a += Vm[i * 10 + k] * Ta[k * 10 + j]; Tb[t] = 0.25f * a; }
    __syncthreads();
    if (act) Vm[t] = Tb[t];
    __syncthreads();
  }
  if (act) invo[(size_t)bh * 100 + t] = Vm[t];
}

// ---------------- k1inv[b,s,h,:] = softmax(Q·Kl^T) @ inv ----------------
__global__ __launch_bounds__(256) void k1inv_kernel(const short* __restrict__ QKV, const float* __restrict__ Kl,
                                                    const float* __restrict__ invg, float* __restrict__ k1inv) {
  int b = blockIdx.y;
  int s0 = blockIdx.x * 16;
  __shared__ float KlS[16 * 650];
  __shared__ float invS[16 * 101];
  for (int idx = threadIdx.x; idx < 16 * 640; idx += 256) {
    int h = idx / 640, r = idx % 640;
    KlS[h * 650 + r] = Kl[(size_t)(b * HH + h) * 640 + r];
  }
  for (int idx = threadIdx.x; idx < 1600; idx += 256) {
    int h = idx / 100, r = idx % 100;
    invS[h * 101 + r] = invg[(size_t)(b * HH + h) * 100 + r];
  }
  __syncthreads();
  int sl = threadIdx.x >> 4, h = threadIdx.x & 15;
  int s = s0 + sl;
  size_t qoff = (size_t)(b * SS + s) * QKV_N + h * HDIM;
  float z[10];
#pragma unroll
  for (int m = 0; m < 10; m++) z[m] = 0.f;
  for (int c = 0; c < 8; c++) {
    short8v qv = *(const short8v*)&QKV[qoff + c * 8];
    float qf[8];
#pragma unroll
    for (int jj = 0; jj < 8; jj++) qf[jj] = bf2f(qv[jj]);
#pragma unroll
    for (int m = 0; m < 10; m++) {
      const float* kl = &KlS[h * 650 + m * 64 + c * 8];
      float a = 0.f;
#pragma unroll
      for (int jj = 0; jj < 8; jj++) a += qf[jj] * kl[jj];
      z[m] += a;
    }
  }
  float mx = z[0];
#pragma unroll
  for (int m = 1; m < 10; m++) mx = fmaxf(mx, z[m]);
  float p[10], ssum = 0.f;
#pragma unroll
  for (int m = 0; m < 10; m++) { p[m] = expf(z[m] - mx); ssum += p[m]; }
  float rinv = 1.f / ssum;
  float* dst = &k1inv[((size_t)(b * SS + s) * HH + h) * MLM];
#pragma unroll
  for (int mm = 0; mm < 10; mm++) {
    float a = 0.f;
#pragma unroll
    for (int jjj = 0; jjj < 10; jjj++) a += p[jjj] * invS[h * 101 + jjj * 10 + mm];
    dst[mm] = a * rinv;
  }
}

// ---------------- kv[b,h,m,:] = softmax_s(Ql·K) @ V  (single-pass) ----------------
__global__ __launch_bounds__(256) void k3v_kernel(const short* __restrict__ QKV, const float* __restrict__ Qlg,
                                                  float* __restrict__ kvout) {
  int bh = blockIdx.x;
  int b = bh >> 4, h = bh & 15;
  __shared__ float Kt[64 * 65];
  __shared__ float Vt[64 * 65];
  __shared__ float eS[10 * 64];
  __shared__ float QlS[640];
  __shared__ float denS[10];
  int tid = threadIdx.x;
  int wave = tid >> 6, lane = tid & 63;
  for (int i = tid; i < 640; i += 256) QlS[i] = Qlg[(size_t)bh * 640 + i];
  float myden = 0.f;
  float accn[3] = {0.f, 0.f, 0.f};
  int rowi = tid >> 2;
  int d0 = (tid & 3) * 16;
  for (int s0 = 0; s0 < SS; s0 += 64) {
    __syncthreads();
    if (s0 + rowi < SS) {
      size_t base = (size_t)(b * SS + s0 + rowi) * QKV_N + h * HDIM + d0;
      short8v k0v = *(const short8v*)&QKV[base + 1024];
      short8v k1v = *(const short8v*)&QKV[base + 1024 + 8];
      short8v v0v = *(const short8v*)&QKV[base + 2048];
      short8v v1v = *(const short8v*)&QKV[base + 2048 + 8];
#pragma unroll
      for (int jj = 0; jj < 8; jj++) {
        Kt[rowi * 65 + d0 + jj]     = bf2f(k0v[jj]);
        Kt[rowi * 65 + d0 + 8 + jj] = bf2f(k1v[jj]);
        Vt[rowi * 65 + d0 + jj]     = bf2f(v0v[jj]);
        Vt[rowi * 65 + d0 + 8 + jj] = bf2f(v1v[jj]);
      }
    }
    __syncthreads();
    for (int mb = 0; mb < 12; mb += 4) {
      int m = mb + wave;
      if (m < 10) {
        float z = 0.f;
        const float* kr = &Kt[lane * 65];
        const float* ql = &QlS[m * 64];
        for (int d = 0; d < 64; d++) z += ql[d] * kr[d];
        eS[m * 64 + lane] = (s0 + lane < SS) ? expf(z) : 0.f;
      }
    }
    __syncthreads();
    if (tid < 10) {
      float a = 0.f;
      for (int slj = 0; slj < 64; slj++) a += eS[tid * 64 + slj];
      myden += a;
    }
#pragma unroll
    for (int ii = 0; ii < 3; ii++) {
      int idx = tid + ii * 256;
      if (idx < 640) {
        int m = idx >> 6, d = idx & 63;
        float a = 0.f;
        for (int slj = 0; slj < 64; slj++) a += eS[m * 64 + slj] * Vt[slj * 65 + d];
        accn[ii] += a;
      }
    }
  }
  if (tid < 10) denS[tid] = myden;
  __syncthreads();
#pragma unroll
  for (int ii = 0; ii < 3; ii++) {
    int idx = tid + ii * 256;
    if (idx < 640) {
      int m = idx >> 6;
      kvout[(size_t)bh * 640 + idx] = accn[ii] / denS[m];
    }
  }
}

// ---------------- attn row = k1inv row @ kv, then LayerNorm(g1,be1) -> bf16 ----------------
__global__ __launch_bounds__(256) void attn_ln1(const float* __restrict__ k1inv, const float* __restrict__ kvg,
                                                const float* __restrict__ g1, const float* __restrict__ be1,
                                                short* __restrict__ h1) {
  int blk = blockIdx.x;
  int b = blk / SS;
  __shared__ float pS[160];
  __shared__ float red[8];
  for (int i = threadIdx.x; i < 160; i += 256) pS[i] = k1inv[(size_t)blk * 160 + i];
  __syncthreads();
  float vals[4], s1 = 0.f, s2 = 0.f;
#pragma unroll
  for (int i = 0; i < 4; i++) {
    int e = threadIdx.x + i * 256;
    int h = e >> 6, d = e & 63;
    const float* kvp = &kvg[((size_t)(b * HH + h) * MLM) * HDIM + d];
    const float* pp = &pS[h * 10];
    float a = 0.f;
#pragma unroll
    for (int m = 0; m < 10; m++) a += pp[m] * kvp[m * 64];
    vals[i] = a; s1 += a; s2 += a * a;
  }
#pragma unroll
  for (int off = 32; off; off >>= 1) { s1 += __shfl_down(s1, off); s2 += __shfl_down(s2, off); }
  int wv = threadIdx.x >> 6;
  if ((threadIdx.x & 63) == 0) { red[wv] = s1; red[4 + wv] = s2; }
  __syncthreads();
  float t1 = red[0] + red[1] + red[2] + red[3];
  float t2 = red[4] + red[5] + red[6] + red[7];
  float mean = t1 * (1.f / 1024.f);
  float var = t2 * (1.f / 1024.f) - mean * mean;
  float ninv = rsqrtf(var + 1e-5f);
#pragma unroll
  for (int i = 0; i < 4; i++) {
    int e = threadIdx.x + i * 256;
    h1[(size_t)blk * EE + e] = f2bf((vals[i] - mean) * ninv * g1[e] + be1[e]);
  }
}

// ---------------- LayerNorm(g2,be2) on f32 rows -> bf16 ----------------
__global__ __launch_bounds__(256) void ln2_kernel(const float* __restrict__ h2, const float* __restrict__ g2,
                                                  const float* __restrict__ be2, short* __restrict__ h3) {
  int blk = blockIdx.x;
  __shared__ float red[8];
  float vals[4], s1 = 0.f, s2 = 0.f;
#pragma unroll
  for (int i = 0; i < 4; i++) {
    int e = threadIdx.x + i * 256;
    float a = h2[(size_t)blk * EE + e];
    vals[i] = a; s1 += a; s2 += a * a;
  }
#pragma unroll
  for (int off = 32; off; off >>= 1) { s1 += __shfl_down(s1, off); s2 += __shfl_down(s2, off); }
  int wv = threadIdx.x >> 6;
  if ((threadIdx.x & 63) == 0) { red[wv] = s1; red[4 + wv] = s2; }
  __syncthreads();
  float t1 = red[0] + red[1] + red[2] + red[3];
  float t2 = red[4] + red[5] + red[6] + red[7];
  float mean = t1 * (1.f / 1024.f);
  float var = t2 * (1.f / 1024.f) - mean * mean;
  float ninv = rsqrtf(var + 1e-5f);
#pragma unroll
  for (int i = 0; i < 4; i++) {
    int e = threadIdx.x + i * 256;
    h3[(size_t)blk * EE + e] = f2bf((vals[i] - mean) * ninv * g2[e] + be2[e]);
  }
}

// ---------------- h3 (B,S,E) bf16 -> out (B,E,S) f32 ----------------
__global__ __launch_bounds__(256) void transpose_out(const short* __restrict__ h3, float* __restrict__ outp) {
  __shared__ short tile[64 * 65];
  int b = blockIdx.z;
  int e0 = blockIdx.y * 64;
  int s0 = blockIdx.x * 64;
  int tx = threadIdx.x & 63;
  int ty = threadIdx.x >> 6;
#pragma unroll
  for (int i = 0; i < 16; i++) {
    int r = ty + i * 4;
    int s = s0 + r;
    if (s < SS) tile[r * 65 + tx] = h3[((size_t)b * SS + s) * EE + e0 + tx];
  }
  __syncthreads();
#pragma unroll
  for (int i = 0; i < 16; i++) {
    int c = ty + i * 4;
    int s = s0 + tx;
    if (s < SS) outp[((size_t)b * EE + e0 + c) * SS + s] = bf2f(tile[tx * 65 + c]);
  }
}

// ---------------- workspace layout (tight aliasing, ~198 MB total) ----------------
#define ALIGN_UP(x) (((x) + 255) & ~(size_t)255)
static const size_t SZ_XB   = (size_t)BB * SS * EE * 2;          // 32.77 MB (slot A: xb -> h1)
static const size_t SZ_WCAT = (size_t)QKV_N * EE * 2;            // 6.29 MB  (slot D: Wcat -> small f32 bufs)
static const size_t SZ_W1B  = (size_t)MLPD * EE * 2;             // 8.39 MB
static const size_t SZ_W2B  = (size_t)EE * MLPD * 2;             // 8.39 MB
static const size_t SZ_QKV  = (size_t)BB * SS * QKV_N * 2;       // 98.3 MB
static const int    CH0_NB  = 63, CH1_NB = 62;                   // 8064 + 7936 = 16000 rows
static const size_t SZ_MID0 = (size_t)CH0_NB * 128 * MLPD * 2;   // 66.06 MB
static const size_t SZ_H2_0 = (size_t)CH0_NB * 128 * EE * 4;     // 33.03 MB
static const size_t SZ_SLOTB = (SZ_QKV > ALIGN_UP(SZ_MID0) + SZ_H2_0)
                               ? SZ_QKV : (ALIGN_UP(SZ_MID0) + SZ_H2_0); // 99.1 MB
static const size_t SZ_QL   = (size_t)BB * HH * MLM * HDIM * 4;  // 327 KB
static const size_t SZ_K2   = (size_t)BB * HH * 100 * 4;
static const size_t SZ_ST   = 512;
static const size_t SZ_K1I  = (size_t)BB * SS * HH * MLM * 4;    // 10.24 MB

extern "C" void kernel_launch(void* const* d_in, const int* in_sizes, int n_in,
                              void* d_out, int out_size, void* d_ws, size_t ws_size,
                              hipStream_t stream) {
  // Inputs are f32 (per reference dtypes); output is f32.
  const float* X   = (const float*)d_in[0];
  const float* Wq  = (const float*)d_in[1];
  const float* bq  = (const float*)d_in[2];
  const float* Wk  = (const float*)d_in[3];
  const float* bk  = (const float*)d_in[4];
  const float* Wv  = (const float*)d_in[5];
  const float* bv  = (const float*)d_in[6];
  const float* g1  = (const float*)d_in[7];
  const float* be1 = (const float*)d_in[8];
  const float* W1  = (const float*)d_in[9];
  const float* b1  = (const float*)d_in[10];
  const float* W2  = (const float*)d_in[11];
  const float* b2  = (const float*)d_in[12];
  const float* g2  = (const float*)d_in[13];
  const float* be2 = (const float*)d_in[14];

  char* ws = (char*)d_ws;
  size_t off = 0;
  // slot A: xb (steps 1-3) -> h1 (steps 9-10)
  char* slotA = ws + off; off += ALIGN_UP(SZ_XB);
  // slot B: qkv (steps 3-8) -> mid_chunk + h2_chunk (steps 10-12)
  char* slotB = ws + off; off += ALIGN_UP(SZ_SLOTB);
  // slot C: h3 (steps 12-13)
  char* slotC = ws + off; off += ALIGN_UP(SZ_XB);
  // slot D: Wcat (steps 2-3) -> Qlm/Klm/k2/stats/inv/kv (steps 4-9)
  char* slotD = ws + off; off += ALIGN_UP(SZ_WCAT);
  short* W1b = (short*)(ws + off); off += ALIGN_UP(SZ_W1B);
  short* W2b = (short*)(ws + off); off += ALIGN_UP(SZ_W2B);
  float* k1ib = (float*)(ws + off); off += ALIGN_UP(SZ_K1I);

  short* xb   = (short*)slotA;
  short* h1   = (short*)slotA;
  short* qkv  = (short*)slotB;
  short* mid  = (short*)slotB;
  float* h2c  = (float*)(slotB + ALIGN_UP(SZ_MID0));
  short* h3   = (short*)slotC;
  short* Wcat = (short*)slotD;
  size_t doff = 0;
  float* Qlm  = (float*)(slotD + doff); doff += ALIGN_UP(SZ_QL);
  float* Klm  = (float*)(slotD + doff); doff += ALIGN_UP(SZ_QL);
  float* k2b  = (float*)(slotD + doff); doff += ALIGN_UP(SZ_K2);
  float* cmaxb= (float*)(slotD + doff); doff += ALIGN_UP(SZ_ST);
  float* rmaxb= (float*)(slotD + doff); doff += ALIGN_UP(SZ_ST);
  float* invb = (float*)(slotD + doff); doff += ALIGN_UP(SZ_K2);
  float* kvb  = (float*)(slotD + doff); doff += ALIGN_UP(SZ_QL);
  (void)ws_size; (void)in_sizes; (void)n_in; (void)out_size;

  // 1. transpose/cast X
  transpose_x<<<dim3(63, 32, BB), dim3(32, 8), 0, stream>>>(X, xb);
  // 2. weight casts f32 -> bf16
  cast_f2b<<<2048, 256, 0, stream>>>(Wq, Wcat,             EE * EE);
  cast_f2b<<<2048, 256, 0, stream>>>(Wk, Wcat + EE * EE,   EE * EE);
  cast_f2b<<<2048, 256, 0, stream>>>(Wv, Wcat + 2*EE*EE,   EE * EE);
  cast_f2b<<<4096, 256, 0, stream>>>(W1, W1b, MLPD * EE);
  cast_f2b<<<4096, 256, 0, stream>>>(W2, W2b, EE * MLPD);
  // 3. QKV projection GEMM (M=16000, N=3072, K=1024)
  gemm_bt<<<dim3(125, 24), 256, 0, stream>>>(xb, Wcat, qkv, EE, QKV_N, 0, bq, bk, bv);
  // 4. landmarks
  landmarks<<<dim3(BB * HH * MLM, 2), 64, 0, stream>>>(qkv, Qlm, Klm);
  // 5. k2 + stats
  k2stats<<<BB * HH, 128, 0, stream>>>(Qlm, Klm, k2b, cmaxb, rmaxb);
  // 6. iterative inverse
  invk<<<BB * HH, 128, 0, stream>>>(k2b, cmaxb, rmaxb, invb);
  // 7. k1 @ inv
  k1inv_kernel<<<dim3(125, BB), 256, 0, stream>>>(qkv, Klm, invb, k1ib);
  // 8. k3 @ V
  k3v_kernel<<<BB * HH, 256, 0, stream>>>(qkv, Qlm, kvb);
  // 9. attn + LN1
  attn_ln1<<<BB * SS, 256, 0, stream>>>(k1ib, kvb, g1, be1, h1);
  // 10-12. MLP + LN2, in two row-chunks so mid+h2 fit in slot B (qkv dead now)
  int row0 = 0;
  for (int c = 0; c < 2; c++) {
    int nb = (c == 0) ? CH0_NB : CH1_NB;
    int rows = nb * 128;
    gemm_bt<<<dim3(nb, 32), 256, 0, stream>>>(h1 + (size_t)row0 * EE, W1b, mid, EE, MLPD, 1, b1, nullptr, nullptr);
    gemm_bt<<<dim3(nb, 8),  256, 0, stream>>>(mid, W2b, h2c, MLPD, EE, 2, b2, nullptr, nullptr);
    ln2_kernel<<<rows, 256, 0, stream>>>(h2c, g2, be2, h3 + (size_t)row0 * EE);
    row0 += rows;
  }
  // 13. transpose to (B,E,S) f32
  transpose_out<<<dim3(32, 16, BB), 256, 0, stream>>>(h3, (float*)d_out);
}

// Round 6
// 1096.863 us; speedup vs baseline: 1.0107x; 1.0107x over previous
//
#include <hip/hip_runtime.h>
#include <cmath>
#include <cstdint>
#include <cstddef>

#define BB 8
#define EE 1024
#define SS 2000
#define HH 16
#define HDIM 64
#define MLM 10
#define MLPD 4096
#define QKV_N 3072
#define QK_SCALE 0.35355339059327373f

typedef __attribute__((ext_vector_type(8))) short short8v;
typedef __attribute__((ext_vector_type(4))) float f32x4;

static __device__ __forceinline__ short f2bf(float x) {
  unsigned u = __builtin_bit_cast(unsigned, x);
  unsigned r = (u + 0x7fffu + ((u >> 16) & 1u)) >> 16;
  return (short)(unsigned short)r;
}
static __device__ __forceinline__ float bf2f(short x) {
  unsigned u = ((unsigned)(unsigned short)x) << 16;
  return __builtin_bit_cast(float, u);
}

// async global->LDS, 16B per lane; LDS dest is wave-uniform base + lane*16
static __device__ __forceinline__ void load_lds16(const short* g, short* l) {
  __builtin_amdgcn_global_load_lds(
      (const __attribute__((address_space(1))) void*)g,
      (__attribute__((address_space(3))) void*)l, 16, 0, 0);
}

// ---------------- X (B,E,S) f32 -> xb (B,S,E) bf16 ----------------
__global__ __launch_bounds__(256) void transpose_x(const float* __restrict__ X, short* __restrict__ xb) {
  __shared__ float tile[32][33];
  int b = blockIdx.z;
  int e0 = blockIdx.y * 32;
  int s0 = blockIdx.x * 32;
  int tx = threadIdx.x;      // 0..31
  int ty = threadIdx.y;      // 0..7
#pragma unroll
  for (int i = 0; i < 32; i += 8) {
    int e = e0 + ty + i, s = s0 + tx;
    tile[ty + i][tx] = (s < SS) ? X[((size_t)b * EE + e) * SS + s] : 0.f;
  }
  __syncthreads();
#pragma unroll
  for (int i = 0; i < 32; i += 8) {
    int s = s0 + ty + i, e = e0 + tx;
    if (s < SS) xb[((size_t)b * SS + s) * EE + e] = f2bf(tile[tx][ty + i]);
  }
}

// ---------------- f32 -> bf16 cast ----------------
__global__ __launch_bounds__(256) void cast_f2b(const float* __restrict__ src, short* __restrict__ dst, int n) {
  int i = blockIdx.x * 256 + threadIdx.x;
  int stride = gridDim.x * 256;
  for (; i < n; i += stride) dst[i] = f2bf(src[i]);
}

// ---------------- bf16 MFMA GEMM: C[m,n] = sum_k A[m,k]*Bm[n,k] ----------------
// global_load_lds width-16 staging (m97 pattern).
// mode 0: QKV  ((acc+bias)*scale for n<2048), bf16 out, N=3072
// mode 1: MLP1 (acc+bias then exact GELU), bf16 out
// mode 2: MLP2 (acc+bias), f32 out
__global__ __launch_bounds__(256) void gemm_bt(
    const short* __restrict__ A, const short* __restrict__ Bm, void* __restrict__ Cv,
    int K, int N, int mode,
    const float* __restrict__ p0, const float* __restrict__ p1, const float* __restrict__ p2)
{
  __shared__ __align__(16) short As[128 * 32];
  __shared__ __align__(16) short Bs[128 * 32];
  int tid = threadIdx.x;
  int m0 = blockIdx.x * 128, n0 = blockIdx.y * 128;
  int wave = tid >> 6, lane = tid & 63;
  int wm = (wave & 1) * 64, wn = (wave >> 1) * 64;
  int lm = lane & 15, quad = lane >> 4;
  // staging: wave w covers rows [w*32, w*32+32) of As and Bs, two 16-row
  // (1024 B contiguous) global_load_lds issues each. lane l reads global row
  // base+l/4, shorts (l%4)*8..+8 -> LDS byte offset lane*16 (row-major 64B rows).
  int lrow = lane >> 2;        // 0..15
  int lcol = (lane & 3) << 3;  // 0,8,16,24
  const short* Ag0 = A + (size_t)(m0 + wave * 32 + lrow) * K + lcol;
  const short* Ag1 = Ag0 + (size_t)16 * K;
  const short* Bg0 = Bm + (size_t)(n0 + wave * 32 + lrow) * K + lcol;
  const short* Bg1 = Bg0 + (size_t)16 * K;
  short* Al0 = &As[(wave * 32) * 32];
  short* Al1 = &As[(wave * 32 + 16) * 32];
  short* Bl0 = &Bs[(wave * 32) * 32];
  short* Bl1 = &Bs[(wave * 32 + 16) * 32];

  f32x4 acc[4][4];
#pragma unroll
  for (int i = 0; i < 4; i++)
#pragma unroll
    for (int j = 0; j < 4; j++) acc[i][j] = (f32x4){0.f, 0.f, 0.f, 0.f};

  for (int k0 = 0; k0 < K; k0 += 32) {
    __syncthreads();
    load_lds16(Ag0 + k0, Al0);
    load_lds16(Ag1 + k0, Al1);
    load_lds16(Bg0 + k0, Bl0);
    load_lds16(Bg1 + k0, Bl1);
    __syncthreads();
    short8v af[4], bfr[4];
#pragma unroll
    for (int i = 0; i < 4; i++) af[i] = *(const short8v*)&As[(wm + i * 16 + lm) * 32 + quad * 8];
#pragma unroll
    for (int j = 0; j < 4; j++) bfr[j] = *(const short8v*)&Bs[(wn + j * 16 + lm) * 32 + quad * 8];
#pragma unroll
    for (int i = 0; i < 4; i++)
#pragma unroll
      for (int j = 0; j < 4; j++)
        acc[i][j] = __builtin_amdgcn_mfma_f32_16x16x32_bf16(af[i], bfr[j], acc[i][j], 0, 0, 0);
  }
#pragma unroll
  for (int i = 0; i < 4; i++) {
#pragma unroll
    for (int j = 0; j < 4; j++) {
      int col = n0 + wn + j * 16 + lm;
      float bias, scl = 1.f;
      if (mode == 0) {
        if (col < 1024)      { bias = p0[col];        scl = QK_SCALE; }
        else if (col < 2048) { bias = p1[col - 1024]; scl = QK_SCALE; }
        else                 { bias = p2[col - 2048]; }
      } else {
        bias = p0[col];
      }
#pragma unroll
      for (int r = 0; r < 4; r++) {
        int row = m0 + wm + i * 16 + quad * 4 + r;
        float v = acc[i][j][r] + bias;
        if (mode == 0)      v *= scl;
        else if (mode == 1) v = 0.5f * v * (1.f + erff(v * 0.70710678118f));
        if (mode == 2) ((float*)Cv)[(size_t)row * N + col] = v;
        else           ((short*)Cv)[(size_t)row * N + col] = f2bf(v);
      }
    }
  }
}

// ---------------- landmarks: mean over 200-row segments ----------------
__global__ __launch_bounds__(64) void landmarks(const short* __restrict__ QKV, float* __restrict__ Ql, float* __restrict__ Kl) {
  int d = threadIdx.x;
  int bhm = blockIdx.x;
  int part = blockIdx.y;
  int b = bhm / (HH * MLM);
  int h = (bhm / MLM) % HH;
  int m = bhm % MLM;
  const short* src = QKV + (part ? 1024 : 0);
  size_t base = ((size_t)(b * SS + m * 200)) * QKV_N + h * HDIM + d;
  float acc = 0.f;
  for (int i = 0; i < 200; i++) acc += bf2f(src[base + (size_t)i * QKV_N]);
  float* dst = part ? Kl : Ql;
  dst[((size_t)(b * HH + h) * MLM + m) * HDIM + d] = acc * (1.f / 200.f);
}

// ---------------- k2 = softmax(Ql Kl^T) + per-bh col-sum/row-sum maxima ----------------
__global__ __launch_bounds__(128) void k2stats(const float* __restrict__ Ql, const float* __restrict__ Kl,
                                               float* __restrict__ k2, float* __restrict__ cmax, float* __restrict__ rmax) {
  int bh = blockIdx.x;
  __shared__ float QlS[640], KlS[640], zz[100], k2s[100], cs[10], rs[10];
  for (int i = threadIdx.x; i < 640; i += 128) {
    QlS[i] = Ql[(size_t)bh * 640 + i];
    KlS[i] = Kl[(size_t)bh * 640 + i];
  }
  __syncthreads();
  if (threadIdx.x < 100) {
    int i = threadIdx.x / 10, j = threadIdx.x % 10;
    float z = 0.f;
    for (int d = 0; d < 64; d++) z += QlS[i * 64 + d] * KlS[j * 64 + d];
    zz[threadIdx.x] = z;
  }
  __syncthreads();
  if (threadIdx.x < 10) {
    int i = threadIdx.x;
    float mx = -1e30f;
    for (int j = 0; j < 10; j++) mx = fmaxf(mx, zz[i * 10 + j]);
    float s = 0.f, e[10];
    for (int j = 0; j < 10; j++) { e[j] = expf(zz[i * 10 + j] - mx); s += e[j]; }
    float inv = 1.f / s, rsum = 0.f;
    for (int j = 0; j < 10; j++) {
      float v = e[j] * inv;
      k2s[i * 10 + j] = v;
      k2[(size_t)bh * 100 + i * 10 + j] = v;
      rsum += v;
    }
    rs[i] = rsum;
  }
  __syncthreads();
  if (threadIdx.x < 10) {
    int j = threadIdx.x;
    float c = 0.f;
    for (int i = 0; i < 10; i++) c += k2s[i * 10 + j];
    cs[j] = c;
  }
  __syncthreads();
  if (threadIdx.x == 0) {
    float m1 = 0.f, m2 = 0.f;
    for (int j = 0; j < 10; j++) { m1 = fmaxf(m1, cs[j]); m2 = fmaxf(m2, rs[j]); }
    cmax[bh] = m1;
    rmax[bh] = m2;
  }
}

// ---------------- Newton-Schulz pseudo-inverse of k2 (10x10), 6 iters ----------------
__global__ __launch_bounds__(128) void invk(const float* __restrict__ k2, const float* __restrict__ cmax,
                                            const float* __restrict__ rmax, float* __restrict__ invo) {
  int bh = blockIdx.x;
  __shared__ float gsc;
  __shared__ float Km[100], Vm[100], KV[100], Ta[100], Tb[100];
  if (threadIdx.x == 0) {
    float mc = 0.f, mr = 0.f;
    for (int i = 0; i < 128; i++) { mc = fmaxf(mc, cmax[i]); mr = fmaxf(mr, rmax[i]); }
    gsc = 1.f / (mc * mr);
  }
  for (int i = threadIdx.x; i < 100; i += 128) Km[i] = k2[(size_t)bh * 100 + i];
  __syncthreads();
  int t = threadIdx.x;
  int i = t / 10, j = t % 10;
  bool act = t < 100;
  if (act) Vm[t] = Km[j * 10 + i] * gsc;
  __syncthreads();
  for (int it = 0; it < 6; it++) {
    if (act) { float a = 0.f; for (int k = 0; k < 10; k++) a += Km[i * 10 + k] * Vm[k * 10 + j]; KV[t] = a; }
    __syncthreads();
    if (act) Ta[t] = (i == j ? 7.f : 0.f) - KV[t];
    __syncthreads();
    if (act) { float a = 0.f; for (int k = 0; k < 10; k++) a += KV[i * 10 + k] * Ta[k * 10 + j]; Tb[t] = (i == j ? 15.f : 0.f) - a; }
    __syncthreads();
    if (act) { float a = 0.f; for (int k = 0; k < 10; k++) a += KV[i * 10 + k] * Tb[k * 10 + j]; Ta[t] = (i == j ? 13.f : 0.f) - a; }
    __syncthreads();
    if (act) { float a = 0.f; for (int k = 0; k < 10; k++) a += Vm[i * 10 + k] * Ta[k * 10 + j]; Tb[t] = 0.25f * a; }
    __syncthreads();
    if (act) Vm[t] = Tb[t];
    __syncthreads();
  }
  if (act) invo[(size_t)bh * 100 + t] = Vm[t];
}

// ---------------- k1inv[b,s,h,:] = softmax(Q·Kl^T) @ inv ----------------
__global__ __launch_bounds__(256) void k1inv_kernel(const short* __restrict__ QKV, const float* __restrict__ Kl,
                                                    const float* __restrict__ invg, float* __restrict__ k1inv) {
  int b = blockIdx.y;
  int s0 = blockIdx.x * 16;
  __shared__ float KlS[16 * 650];
  __shared__ float invS[16 * 101];
  for (int idx = threadIdx.x; idx < 16 * 640; idx += 256) {
    int h = idx / 640, r = idx % 640;
    KlS[h * 650 + r] = Kl[(size_t)(b * HH + h) * 640 + r];
  }
  for (int idx = threadIdx.x; idx < 1600; idx += 256) {
    int h = idx / 100, r = idx % 100;
    invS[h * 101 + r] = invg[(size_t)(b * HH + h) * 100 + r];
  }
  __syncthreads();
  int sl = threadIdx.x >> 4, h = threadIdx.x & 15;
  int s = s0 + sl;
  size_t qoff = (size_t)(b * SS + s) * QKV_N + h * HDIM;
  float z[10];
#pragma unroll
  for (int m = 0; m < 10; m++) z[m] = 0.f;
  for (int c = 0; c < 8; c++) {
    short8v qv = *(const short8v*)&QKV[qoff + c * 8];
    float qf[8];
#pragma unroll
    for (int jj = 0; jj < 8; jj++) qf[jj] = bf2f(qv[jj]);
#pragma unroll
    for (int m = 0; m < 10; m++) {
      const float* kl = &KlS[h * 650 + m * 64 + c * 8];
      float a = 0.f;
#pragma unroll
      for (int jj = 0; jj < 8; jj++) a += qf[jj] * kl[jj];
      z[m] += a;
    }
  }
  float mx = z[0];
#pragma unroll
  for (int m = 1; m < 10; m++) mx = fmaxf(mx, z[m]);
  float p[10], ssum = 0.f;
#pragma unroll
  for (int m = 0; m < 10; m++) { p[m] = expf(z[m] - mx); ssum += p[m]; }
  float rinv = 1.f / ssum;
  float* dst = &k1inv[((size_t)(b * SS + s) * HH + h) * MLM];
#pragma unroll
  for (int mm = 0; mm < 10; mm++) {
    float a = 0.f;
#pragma unroll
    for (int jjj = 0; jjj < 10; jjj++) a += p[jjj] * invS[h * 101 + jjj * 10 + mm];
    dst[mm] = a * rinv;
  }
}

// ---------------- kv[b,h,m,:] = softmax_s(Ql·K) @ V  (single-pass) ----------------
__global__ __launch_bounds__(256) void k3v_kernel(const short* __restrict__ QKV, const float* __restrict__ Qlg,
                                                  float* __restrict__ kvout) {
  int bh = blockIdx.x;
  int b = bh >> 4, h = bh & 15;
  __shared__ float Kt[64 * 65];
  __shared__ float Vt[64 * 65];
  __shared__ float eS[10 * 64];
  __shared__ float QlS[640];
  __shared__ float denS[10];
  int tid = threadIdx.x;
  int wave = tid >> 6, lane = tid & 63;
  for (int i = tid; i < 640; i += 256) QlS[i] = Qlg[(size_t)bh * 640 + i];
  float myden = 0.f;
  float accn[3] = {0.f, 0.f, 0.f};
  int rowi = tid >> 2;
  int d0 = (tid & 3) * 16;
  for (int s0 = 0; s0 < SS; s0 += 64) {
    __syncthreads();
    if (s0 + rowi < SS) {
      size_t base = (size_t)(b * SS + s0 + rowi) * QKV_N + h * HDIM + d0;
      short8v k0v = *(const short8v*)&QKV[base + 1024];
      short8v k1v = *(const short8v*)&QKV[base + 1024 + 8];
      short8v v0v = *(const short8v*)&QKV[base + 2048];
      short8v v1v = *(const short8v*)&QKV[base + 2048 + 8];
#pragma unroll
      for (int jj = 0; jj < 8; jj++) {
        Kt[rowi * 65 + d0 + jj]     = bf2f(k0v[jj]);
        Kt[rowi * 65 + d0 + 8 + jj] = bf2f(k1v[jj]);
        Vt[rowi * 65 + d0 + jj]     = bf2f(v0v[jj]);
        Vt[rowi * 65 + d0 + 8 + jj] = bf2f(v1v[jj]);
      }
    }
    __syncthreads();
    for (int mb = 0; mb < 12; mb += 4) {
      int m = mb + wave;
      if (m < 10) {
        float z = 0.f;
        const float* kr = &Kt[lane * 65];
        const float* ql = &QlS[m * 64];
        for (int d = 0; d < 64; d++) z += ql[d] * kr[d];
        eS[m * 64 + lane] = (s0 + lane < SS) ? expf(z) : 0.f;
      }
    }
    __syncthreads();
    if (tid < 10) {
      float a = 0.f;
      for (int slj = 0; slj < 64; slj++) a += eS[tid * 64 + slj];
      myden += a;
    }
#pragma unroll
    for (int ii = 0; ii < 3; ii++) {
      int idx = tid + ii * 256;
      if (idx < 640) {
        int m = idx >> 6, d = idx & 63;
        float a = 0.f;
        for (int slj = 0; slj < 64; slj++) a += eS[m * 64 + slj] * Vt[slj * 65 + d];
        accn[ii] += a;
      }
    }
  }
  if (tid < 10) denS[tid] = myden;
  __syncthreads();
#pragma unroll
  for (int ii = 0; ii < 3; ii++) {
    int idx = tid + ii * 256;
    if (idx < 640) {
      int m = idx >> 6;
      kvout[(size_t)bh * 640 + idx] = accn[ii] / denS[m];
    }
  }
}

// ---------------- attn row = k1inv row @ kv, then LayerNorm(g1,be1) -> bf16 ----------------
__global__ __launch_bounds__(256) void attn_ln1(const float* __restrict__ k1inv, const float* __restrict__ kvg,
                                                const float* __restrict__ g1, const float* __restrict__ be1,
                                                short* __restrict__ h1) {
  int blk = blockIdx.x;
  int b = blk / SS;
  __shared__ float pS[160];
  __shared__ float red[8];
  for (int i = threadIdx.x; i < 160; i += 256) pS[i] = k1inv[(size_t)blk * 160 + i];
  __syncthreads();
  float vals[4], s1 = 0.f, s2 = 0.f;
#pragma unroll
  for (int i = 0; i < 4; i++) {
    int e = threadIdx.x + i * 256;
    int h = e >> 6, d = e & 63;
    const float* kvp = &kvg[((size_t)(b * HH + h) * MLM) * HDIM + d];
    const float* pp = &pS[h * 10];
    float a = 0.f;
#pragma unroll
    for (int m = 0; m < 10; m++) a += pp[m] * kvp[m * 64];
    vals[i] = a; s1 += a; s2 += a * a;
  }
#pragma unroll
  for (int off = 32; off; off >>= 1) { s1 += __shfl_down(s1, off); s2 += __shfl_down(s2, off); }
  int wv = threadIdx.x >> 6;
  if ((threadIdx.x & 63) == 0) { red[wv] = s1; red[4 + wv] = s2; }
  __syncthreads();
  float t1 = red[0] + red[1] + red[2] + red[3];
  float t2 = red[4] + red[5] + red[6] + red[7];
  float mean = t1 * (1.f / 1024.f);
  float var = t2 * (1.f / 1024.f) - mean * mean;
  float ninv = rsqrtf(var + 1e-5f);
#pragma unroll
  for (int i = 0; i < 4; i++) {
    int e = threadIdx.x + i * 256;
    h1[(size_t)blk * EE + e] = f2bf((vals[i] - mean) * ninv * g1[e] + be1[e]);
  }
}

// ---------------- LayerNorm(g2,be2) on f32 rows -> bf16 ----------------
__global__ __launch_bounds__(256) void ln2_kernel(const float* __restrict__ h2, const float* __restrict__ g2,
                                                  const float* __restrict__ be2, short* __restrict__ h3) {
  int blk = blockIdx.x;
  __shared__ float red[8];
  float vals[4], s1 = 0.f, s2 = 0.f;
#pragma unroll
  for (int i = 0; i < 4; i++) {
    int e = threadIdx.x + i * 256;
    float a = h2[(size_t)blk * EE + e];
    vals[i] = a; s1 += a; s2 += a * a;
  }
#pragma unroll
  for (int off = 32; off; off >>= 1) { s1 += __shfl_down(s1, off); s2 += __shfl_down(s2, off); }
  int wv = threadIdx.x >> 6;
  if ((threadIdx.x & 63) == 0) { red[wv] = s1; red[4 + wv] = s2; }
  __syncthreads();
  float t1 = red[0] + red[1] + red[2] + red[3];
  float t2 = red[4] + red[5] + red[6] + red[7];
  float mean = t1 * (1.f / 1024.f);
  float var = t2 * (1.f / 1024.f) - mean * mean;
  float ninv = rsqrtf(var + 1e-5f);
#pragma unroll
  for (int i = 0; i < 4; i++) {
    int e = threadIdx.x + i * 256;
    h3[(size_t)blk * EE + e] = f2bf((vals[i] - mean) * ninv * g2[e] + be2[e]);
  }
}

// ---------------- h3 (B,S,E) bf16 -> out (B,E,S) f32 ----------------
__global__ __launch_bounds__(256) void transpose_out(const short* __restrict__ h3, float* __restrict__ outp) {
  __shared__ short tile[64 * 65];
  int b = blockIdx.z;
  int e0 = blockIdx.y * 64;
  int s0 = blockIdx.x * 64;
  int tx = threadIdx.x & 63;
  int ty = threadIdx.x >> 6;
#pragma unroll
  for (int i = 0; i < 16; i++) {
    int r = ty + i * 4;
    int s = s0 + r;
    if (s < SS) tile[r * 65 + tx] = h3[((size_t)b * SS + s) * EE + e0 + tx];
  }
  __syncthreads();
#pragma unroll
  for (int i = 0; i < 16; i++) {
    int c = ty + i * 4;
    int s = s0 + tx;
    if (s < SS) outp[((size_t)b * EE + e0 + c) * SS + s] = bf2f(tile[tx * 65 + c]);
  }
}

// ---------------- workspace layout (tight aliasing, ~198 MB total) ----------------
#define ALIGN_UP(x) (((x) + 255) & ~(size_t)255)
static const size_t SZ_XB   = (size_t)BB * SS * EE * 2;          // 32.77 MB (slot A: xb -> h1)
static const size_t SZ_WCAT = (size_t)QKV_N * EE * 2;            // 6.29 MB  (slot D)
static const size_t SZ_W1B  = (size_t)MLPD * EE * 2;             // 8.39 MB
static const size_t SZ_W2B  = (size_t)EE * MLPD * 2;             // 8.39 MB
static const size_t SZ_QKV  = (size_t)BB * SS * QKV_N * 2;       // 98.3 MB
static const int    CH0_NB  = 63, CH1_NB = 62;                   // 8064 + 7936 = 16000 rows
static const size_t SZ_MID0 = (size_t)CH0_NB * 128 * MLPD * 2;   // 66.06 MB
static const size_t SZ_H2_0 = (size_t)CH0_NB * 128 * EE * 4;     // 33.03 MB
static const size_t SZ_SLOTB = (SZ_QKV > ALIGN_UP(SZ_MID0) + SZ_H2_0)
                               ? SZ_QKV : (ALIGN_UP(SZ_MID0) + SZ_H2_0); // 99.1 MB
static const size_t SZ_QL   = (size_t)BB * HH * MLM * HDIM * 4;  // 327 KB
static const size_t SZ_K2   = (size_t)BB * HH * 100 * 4;
static const size_t SZ_ST   = 512;
static const size_t SZ_K1I  = (size_t)BB * SS * HH * MLM * 4;    // 10.24 MB

extern "C" void kernel_launch(void* const* d_in, const int* in_sizes, int n_in,
                              void* d_out, int out_size, void* d_ws, size_t ws_size,
                              hipStream_t stream) {
  // Inputs f32; output f32.
  const float* X   = (const float*)d_in[0];
  const float* Wq  = (const float*)d_in[1];
  const float* bq  = (const float*)d_in[2];
  const float* Wk  = (const float*)d_in[3];
  const float* bk  = (const float*)d_in[4];
  const float* Wv  = (const float*)d_in[5];
  const float* bv  = (const float*)d_in[6];
  const float* g1  = (const float*)d_in[7];
  const float* be1 = (const float*)d_in[8];
  const float* W1  = (const float*)d_in[9];
  const float* b1  = (const float*)d_in[10];
  const float* W2  = (const float*)d_in[11];
  const float* b2  = (const float*)d_in[12];
  const float* g2  = (const float*)d_in[13];
  const float* be2 = (const float*)d_in[14];

  char* ws = (char*)d_ws;
  size_t off = 0;
  char* slotA = ws + off; off += ALIGN_UP(SZ_XB);     // xb -> h1
  char* slotB = ws + off; off += ALIGN_UP(SZ_SLOTB);  // qkv -> mid+h2 chunks
  char* slotC = ws + off; off += ALIGN_UP(SZ_XB);     // h3
  char* slotD = ws + off; off += ALIGN_UP(SZ_WCAT);   // Wcat -> small f32 bufs
  short* W1b = (short*)(ws + off); off += ALIGN_UP(SZ_W1B);
  short* W2b = (short*)(ws + off); off += ALIGN_UP(SZ_W2B);
  float* k1ib = (float*)(ws + off); off += ALIGN_UP(SZ_K1I);

  short* xb   = (short*)slotA;
  short* h1   = (short*)slotA;
  short* qkv  = (short*)slotB;
  short* mid  = (short*)slotB;
  float* h2c  = (float*)(slotB + ALIGN_UP(SZ_MID0));
  short* h3   = (short*)slotC;
  short* Wcat = (short*)slotD;
  size_t doff = 0;
  float* Qlm  = (float*)(slotD + doff); doff += ALIGN_UP(SZ_QL);
  float* Klm  = (float*)(slotD + doff); doff += ALIGN_UP(SZ_QL);
  float* k2b  = (float*)(slotD + doff); doff += ALIGN_UP(SZ_K2);
  float* cmaxb= (float*)(slotD + doff); doff += ALIGN_UP(SZ_ST);
  float* rmaxb= (float*)(slotD + doff); doff += ALIGN_UP(SZ_ST);
  float* invb = (float*)(slotD + doff); doff += ALIGN_UP(SZ_K2);
  float* kvb  = (float*)(slotD + doff); doff += ALIGN_UP(SZ_QL);
  (void)ws_size; (void)in_sizes; (void)n_in; (void)out_size;

  // 1. transpose/cast X
  transpose_x<<<dim3(63, 32, BB), dim3(32, 8), 0, stream>>>(X, xb);
  // 2. weight casts f32 -> bf16
  cast_f2b<<<2048, 256, 0, stream>>>(Wq, Wcat,             EE * EE);
  cast_f2b<<<2048, 256, 0, stream>>>(Wk, Wcat + EE * EE,   EE * EE);
  cast_f2b<<<2048, 256, 0, stream>>>(Wv, Wcat + 2*EE*EE,   EE * EE);
  cast_f2b<<<4096, 256, 0, stream>>>(W1, W1b, MLPD * EE);
  cast_f2b<<<4096, 256, 0, stream>>>(W2, W2b, EE * MLPD);
  // 3. QKV projection GEMM (M=16000, N=3072, K=1024)
  gemm_bt<<<dim3(125, 24), 256, 0, stream>>>(xb, Wcat, qkv, EE, QKV_N, 0, bq, bk, bv);
  // 4. landmarks
  landmarks<<<dim3(BB * HH * MLM, 2), 64, 0, stream>>>(qkv, Qlm, Klm);
  // 5. k2 + stats
  k2stats<<<BB * HH, 128, 0, stream>>>(Qlm, Klm, k2b, cmaxb, rmaxb);
  // 6. iterative inverse
  invk<<<BB * HH, 128, 0, stream>>>(k2b, cmaxb, rmaxb, invb);
  // 7. k1 @ inv
  k1inv_kernel<<<dim3(125, BB), 256, 0, stream>>>(qkv, Klm, invb, k1ib);
  // 8. k3 @ V
  k3v_kernel<<<BB * HH, 256, 0, stream>>>(qkv, Qlm, kvb);
  // 9. attn + LN1
  attn_ln1<<<BB * SS, 256, 0, stream>>>(k1ib, kvb, g1, be1, h1);
  // 10-12. MLP + LN2, in two row-chunks (qkv dead now)
  int row0 = 0;
  for (int c = 0; c < 2; c++) {
    int nb = (c == 0) ? CH0_NB : CH1_NB;
    int rows = nb * 128;
    gemm_bt<<<dim3(nb, 32), 256, 0, stream>>>(h1 + (size_t)row0 * EE, W1b, mid, EE, MLPD, 1, b1, nullptr, nullptr);
    gemm_bt<<<dim3(nb, 8),  256, 0, stream>>>(mid, W2b, h2c, MLPD, EE, 2, b2, nullptr, nullptr);
    ln2_kernel<<<rows, 256, 0, stream>>>(h2c, g2, be2, h3 + (size_t)row0 * EE);
    row0 += rows;
  }
  // 13. transpose to (B,E,S) f32
  transpose_out<<<dim3(32, 16, BB), 256, 0, stream>>>(h3, (float*)d_out);
}

// Round 7
// 1049.626 us; speedup vs baseline: 1.0562x; 1.0450x over previous
//
#include <hip/hip_runtime.h>
#include <cmath>
#include <cstdint>
#include <cstddef>

#define BB 8
#define EE 1024
#define SS 2000
#define HH 16
#define HDIM 64
#define MLM 10
#define MLPD 4096
#define QKV_N 3072
#define QK_SCALE 0.35355339059327373f

typedef __attribute__((ext_vector_type(8))) short short8v;
typedef __attribute__((ext_vector_type(4))) float f32x4;

static __device__ __forceinline__ short f2bf(float x) {
  unsigned u = __builtin_bit_cast(unsigned, x);
  unsigned r = (u + 0x7fffu + ((u >> 16) & 1u)) >> 16;
  return (short)(unsigned short)r;
}
static __device__ __forceinline__ float bf2f(short x) {
  unsigned u = ((unsigned)(unsigned short)x) << 16;
  return __builtin_bit_cast(float, u);
}

// async global->LDS, 16B per lane; LDS dest is wave-uniform base + lane*16
static __device__ __forceinline__ void load_lds16(const short* g, short* l) {
  __builtin_amdgcn_global_load_lds(
      (const __attribute__((address_space(1))) void*)g,
      (__attribute__((address_space(3))) void*)l, 16, 0, 0);
}

// ---------------- X (B,E,S) f32 -> xb (B,S,E) bf16 ----------------
__global__ __launch_bounds__(256) void transpose_x(const float* __restrict__ X, short* __restrict__ xb) {
  __shared__ float tile[32][33];
  int b = blockIdx.z;
  int e0 = blockIdx.y * 32;
  int s0 = blockIdx.x * 32;
  int tx = threadIdx.x;      // 0..31
  int ty = threadIdx.y;      // 0..7
#pragma unroll
  for (int i = 0; i < 32; i += 8) {
    int e = e0 + ty + i, s = s0 + tx;
    tile[ty + i][tx] = (s < SS) ? X[((size_t)b * EE + e) * SS + s] : 0.f;
  }
  __syncthreads();
#pragma unroll
  for (int i = 0; i < 32; i += 8) {
    int s = s0 + ty + i, e = e0 + tx;
    if (s < SS) xb[((size_t)b * SS + s) * EE + e] = f2bf(tile[tx][ty + i]);
  }
}

// ---------------- f32 -> bf16 cast ----------------
__global__ __launch_bounds__(256) void cast_f2b(const float* __restrict__ src, short* __restrict__ dst, int n) {
  int i = blockIdx.x * 256 + threadIdx.x;
  int stride = gridDim.x * 256;
  for (; i < n; i += stride) dst[i] = f2bf(src[i]);
}

// ---------------- bf16 MFMA GEMM: C[m,n] = sum_k A[m,k]*Bm[n,k] ----------------
// 1-D grid, XCD/L2-aware remap: consecutive blockIdx round-robin over 8 XCDs;
// each XCD owns a fixed N-slice (NT_N/8 n-tiles -> ~1 MB of B resident in its
// 4 MB L2) and sweeps M slowly (each A-tile reused ntX times back-to-back).
// mode 0: QKV  ((acc+bias)*scale for n<2048), bf16 out
// mode 1: MLP1 (acc+bias then exact GELU), bf16 out
// mode 2: MLP2 (acc+bias), f32 out
__global__ __launch_bounds__(256) void gemm_bt(
    const short* __restrict__ A, const short* __restrict__ Bm, void* __restrict__ Cv,
    int K, int N, int mode,
    const float* __restrict__ p0, const float* __restrict__ p1, const float* __restrict__ p2)
{
  __shared__ __align__(16) short As[128 * 32];
  __shared__ __align__(16) short Bs[128 * 32];
  int tid = threadIdx.x;
  // ---- XCD-aware tile mapping (grid must be divisible by 8; NT_N by 8) ----
  int NT_N = N >> 7;
  int ntX = NT_N >> 3;            // n-tiles per XCD
  int lin = blockIdx.x;
  int xcd = lin & 7;
  int idx = lin >> 3;
  int m0 = (idx / ntX) * 128;
  int n0 = (xcd * ntX + (idx % ntX)) * 128;

  int wave = tid >> 6, lane = tid & 63;
  int wm = (wave & 1) * 64, wn = (wave >> 1) * 64;
  int lm = lane & 15, quad = lane >> 4;
  int lrow = lane >> 2;        // 0..15
  int lcol = (lane & 3) << 3;  // 0,8,16,24
  const short* Ag0 = A + (size_t)(m0 + wave * 32 + lrow) * K + lcol;
  const short* Ag1 = Ag0 + (size_t)16 * K;
  const short* Bg0 = Bm + (size_t)(n0 + wave * 32 + lrow) * K + lcol;
  const short* Bg1 = Bg0 + (size_t)16 * K;
  short* Al0 = &As[(wave * 32) * 32];
  short* Al1 = &As[(wave * 32 + 16) * 32];
  short* Bl0 = &Bs[(wave * 32) * 32];
  short* Bl1 = &Bs[(wave * 32 + 16) * 32];

  f32x4 acc[4][4];
#pragma unroll
  for (int i = 0; i < 4; i++)
#pragma unroll
    for (int j = 0; j < 4; j++) acc[i][j] = (f32x4){0.f, 0.f, 0.f, 0.f};

  for (int k0 = 0; k0 < K; k0 += 32) {
    __syncthreads();
    load_lds16(Ag0 + k0, Al0);
    load_lds16(Ag1 + k0, Al1);
    load_lds16(Bg0 + k0, Bl0);
    load_lds16(Bg1 + k0, Bl1);
    __syncthreads();
    short8v af[4], bfr[4];
#pragma unroll
    for (int i = 0; i < 4; i++) af[i] = *(const short8v*)&As[(wm + i * 16 + lm) * 32 + quad * 8];
#pragma unroll
    for (int j = 0; j < 4; j++) bfr[j] = *(const short8v*)&Bs[(wn + j * 16 + lm) * 32 + quad * 8];
#pragma unroll
    for (int i = 0; i < 4; i++)
#pragma unroll
      for (int j = 0; j < 4; j++)
        acc[i][j] = __builtin_amdgcn_mfma_f32_16x16x32_bf16(af[i], bfr[j], acc[i][j], 0, 0, 0);
  }
#pragma unroll
  for (int i = 0; i < 4; i++) {
#pragma unroll
    for (int j = 0; j < 4; j++) {
      int col = n0 + wn + j * 16 + lm;
      float bias, scl = 1.f;
      if (mode == 0) {
        if (col < 1024)      { bias = p0[col];        scl = QK_SCALE; }
        else if (col < 2048) { bias = p1[col - 1024]; scl = QK_SCALE; }
        else                 { bias = p2[col - 2048]; }
      } else {
        bias = p0[col];
      }
#pragma unroll
      for (int r = 0; r < 4; r++) {
        int row = m0 + wm + i * 16 + quad * 4 + r;
        float v = acc[i][j][r] + bias;
        if (mode == 0)      v *= scl;
        else if (mode == 1) v = 0.5f * v * (1.f + erff(v * 0.70710678118f));
        if (mode == 2) ((float*)Cv)[(size_t)row * N + col] = v;
        else           ((short*)Cv)[(size_t)row * N + col] = f2bf(v);
      }
    }
  }
}

// ---------------- landmarks: mean over 200-row segments ----------------
__global__ __launch_bounds__(64) void landmarks(const short* __restrict__ QKV, float* __restrict__ Ql, float* __restrict__ Kl) {
  int d = threadIdx.x;
  int bhm = blockIdx.x;
  int part = blockIdx.y;
  int b = bhm / (HH * MLM);
  int h = (bhm / MLM) % HH;
  int m = bhm % MLM;
  const short* src = QKV + (part ? 1024 : 0);
  size_t base = ((size_t)(b * SS + m * 200)) * QKV_N + h * HDIM + d;
  float acc = 0.f;
  for (int i = 0; i < 200; i++) acc += bf2f(src[base + (size_t)i * QKV_N]);
  float* dst = part ? Kl : Ql;
  dst[((size_t)(b * HH + h) * MLM + m) * HDIM + d] = acc * (1.f / 200.f);
}

// ---------------- k2 = softmax(Ql Kl^T) + per-bh col-sum/row-sum maxima ----------------
__global__ __launch_bounds__(128) void k2stats(const float* __restrict__ Ql, const float* __restrict__ Kl,
                                               float* __restrict__ k2, float* __restrict__ cmax, float* __restrict__ rmax) {
  int bh = blockIdx.x;
  __shared__ float QlS[640], KlS[640], zz[100], k2s[100], cs[10], rs[10];
  for (int i = threadIdx.x; i < 640; i += 128) {
    QlS[i] = Ql[(size_t)bh * 640 + i];
    KlS[i] = Kl[(size_t)bh * 640 + i];
  }
  __syncthreads();
  if (threadIdx.x < 100) {
    int i = threadIdx.x / 10, j = threadIdx.x % 10;
    float z = 0.f;
    for (int d = 0; d < 64; d++) z += QlS[i * 64 + d] * KlS[j * 64 + d];
    zz[threadIdx.x] = z;
  }
  __syncthreads();
  if (threadIdx.x < 10) {
    int i = threadIdx.x;
    float mx = -1e30f;
    for (int j = 0; j < 10; j++) mx = fmaxf(mx, zz[i * 10 + j]);
    float s = 0.f, e[10];
    for (int j = 0; j < 10; j++) { e[j] = expf(zz[i * 10 + j] - mx); s += e[j]; }
    float inv = 1.f / s, rsum = 0.f;
    for (int j = 0; j < 10; j++) {
      float v = e[j] * inv;
      k2s[i * 10 + j] = v;
      k2[(size_t)bh * 100 + i * 10 + j] = v;
      rsum += v;
    }
    rs[i] = rsum;
  }
  __syncthreads();
  if (threadIdx.x < 10) {
    int j = threadIdx.x;
    float c = 0.f;
    for (int i = 0; i < 10; i++) c += k2s[i * 10 + j];
    cs[j] = c;
  }
  __syncthreads();
  if (threadIdx.x == 0) {
    float m1 = 0.f, m2 = 0.f;
    for (int j = 0; j < 10; j++) { m1 = fmaxf(m1, cs[j]); m2 = fmaxf(m2, rs[j]); }
    cmax[bh] = m1;
    rmax[bh] = m2;
  }
}

// ---------------- Newton-Schulz pseudo-inverse of k2 (10x10), 6 iters ----------------
__global__ __launch_bounds__(128) void invk(const float* __restrict__ k2, const float* __restrict__ cmax,
                                            const float* __restrict__ rmax, float* __restrict__ invo) {
  int bh = blockIdx.x;
  __shared__ float gsc;
  __shared__ float Km[100], Vm[100], KV[100], Ta[100], Tb[100];
  if (threadIdx.x == 0) {
    float mc = 0.f, mr = 0.f;
    for (int i = 0; i < 128; i++) { mc = fmaxf(mc, cmax[i]); mr = fmaxf(mr, rmax[i]); }
    gsc = 1.f / (mc * mr);
  }
  for (int i = threadIdx.x; i < 100; i += 128) Km[i] = k2[(size_t)bh * 100 + i];
  __syncthreads();
  int t = threadIdx.x;
  int i = t / 10, j = t % 10;
  bool act = t < 100;
  if (act) Vm[t] = Km[j * 10 + i] * gsc;
  __syncthreads();
  for (int it = 0; it < 6; it++) {
    if (act) { float a = 0.f; for (int k = 0; k < 10; k++) a += Km[i * 10 + k] * Vm[k * 10 + j]; KV[t] = a; }
    __syncthreads();
    if (act) Ta[t] = (i == j ? 7.f : 0.f) - KV[t];
    __syncthreads();
    if (act) { float a = 0.f; for (int k = 0; k < 10; k++) a += KV[i * 10 + k] * Ta[k * 10 + j]; Tb[t] = (i == j ? 15.f : 0.f) - a; }
    __syncthreads();
    if (act) { float a = 0.f; for (int k = 0; k < 10; k++) a += KV[i * 10 + k] * Tb[k * 10 + j]; Ta[t] = (i == j ? 13.f : 0.f) - a; }
    __syncthreads();
    if (act) { float a = 0.f; for (int k = 0; k < 10; k++) a += Vm[i * 10 + k] * Ta[k * 10 + j]; Tb[t] = 0.25f * a; }
    __syncthreads();
    if (act) Vm[t] = Tb[t];
    __syncthreads();
  }
  if (act) invo[(size_t)bh * 100 + t] = Vm[t];
}

// ---------------- k1inv[b,s,h,:] = softmax(Q·Kl^T) @ inv ----------------
__global__ __launch_bounds__(256) void k1inv_kernel(const short* __restrict__ QKV, const float* __restrict__ Kl,
                                                    const float* __restrict__ invg, float* __restrict__ k1inv) {
  int b = blockIdx.y;
  int s0 = blockIdx.x * 16;
  __shared__ float KlS[16 * 650];
  __shared__ float invS[16 * 101];
  for (int idx = threadIdx.x; idx < 16 * 640; idx += 256) {
    int h = idx / 640, r = idx % 640;
    KlS[h * 650 + r] = Kl[(size_t)(b * HH + h) * 640 + r];
  }
  for (int idx = threadIdx.x; idx < 1600; idx += 256) {
    int h = idx / 100, r = idx % 100;
    invS[h * 101 + r] = invg[(size_t)(b * HH + h) * 100 + r];
  }
  __syncthreads();
  int sl = threadIdx.x >> 4, h = threadIdx.x & 15;
  int s = s0 + sl;
  size_t qoff = (size_t)(b * SS + s) * QKV_N + h * HDIM;
  float z[10];
#pragma unroll
  for (int m = 0; m < 10; m++) z[m] = 0.f;
  for (int c = 0; c < 8; c++) {
    short8v qv = *(const short8v*)&QKV[qoff + c * 8];
    float qf[8];
#pragma unroll
    for (int jj = 0; jj < 8; jj++) qf[jj] = bf2f(qv[jj]);
#pragma unroll
    for (int m = 0; m < 10; m++) {
      const float* kl = &KlS[h * 650 + m * 64 + c * 8];
      float a = 0.f;
#pragma unroll
      for (int jj = 0; jj < 8; jj++) a += qf[jj] * kl[jj];
      z[m] += a;
    }
  }
  float mx = z[0];
#pragma unroll
  for (int m = 1; m < 10; m++) mx = fmaxf(mx, z[m]);
  float p[10], ssum = 0.f;
#pragma unroll
  for (int m = 0; m < 10; m++) { p[m] = expf(z[m] - mx); ssum += p[m]; }
  float rinv = 1.f / ssum;
  float* dst = &k1inv[((size_t)(b * SS + s) * HH + h) * MLM];
#pragma unroll
  for (int mm = 0; mm < 10; mm++) {
    float a = 0.f;
#pragma unroll
    for (int jjj = 0; jjj < 10; jjj++) a += p[jjj] * invS[h * 101 + jjj * 10 + mm];
    dst[mm] = a * rinv;
  }
}

// ---------------- kv[b,h,m,:] = softmax_s(Ql·K) @ V  (single-pass) ----------------
__global__ __launch_bounds__(256) void k3v_kernel(const short* __restrict__ QKV, const float* __restrict__ Qlg,
                                                  float* __restrict__ kvout) {
  int bh = blockIdx.x;
  int b = bh >> 4, h = bh & 15;
  __shared__ float Kt[64 * 65];
  __shared__ float Vt[64 * 65];
  __shared__ float eS[10 * 64];
  __shared__ float QlS[640];
  __shared__ float denS[10];
  int tid = threadIdx.x;
  int wave = tid >> 6, lane = tid & 63;
  for (int i = tid; i < 640; i += 256) QlS[i] = Qlg[(size_t)bh * 640 + i];
  float myden = 0.f;
  float accn[3] = {0.f, 0.f, 0.f};
  int rowi = tid >> 2;
  int d0 = (tid & 3) * 16;
  for (int s0 = 0; s0 < SS; s0 += 64) {
    __syncthreads();
    if (s0 + rowi < SS) {
      size_t base = (size_t)(b * SS + s0 + rowi) * QKV_N + h * HDIM + d0;
      short8v k0v = *(const short8v*)&QKV[base + 1024];
      short8v k1v = *(const short8v*)&QKV[base + 1024 + 8];
      short8v v0v = *(const short8v*)&QKV[base + 2048];
      short8v v1v = *(const short8v*)&QKV[base + 2048 + 8];
#pragma unroll
      for (int jj = 0; jj < 8; jj++) {
        Kt[rowi * 65 + d0 + jj]     = bf2f(k0v[jj]);
        Kt[rowi * 65 + d0 + 8 + jj] = bf2f(k1v[jj]);
        Vt[rowi * 65 + d0 + jj]     = bf2f(v0v[jj]);
        Vt[rowi * 65 + d0 + 8 + jj] = bf2f(v1v[jj]);
      }
    }
    __syncthreads();
    for (int mb = 0; mb < 12; mb += 4) {
      int m = mb + wave;
      if (m < 10) {
        float z = 0.f;
        const float* kr = &Kt[lane * 65];
        const float* ql = &QlS[m * 64];
        for (int d = 0; d < 64; d++) z += ql[d] * kr[d];
        eS[m * 64 + lane] = (s0 + lane < SS) ? expf(z) : 0.f;
      }
    }
    __syncthreads();
    if (tid < 10) {
      float a = 0.f;
      for (int slj = 0; slj < 64; slj++) a += eS[tid * 64 + slj];
      myden += a;
    }
#pragma unroll
    for (int ii = 0; ii < 3; ii++) {
      int idx = tid + ii * 256;
      if (idx < 640) {
        int m = idx >> 6, d = idx & 63;
        float a = 0.f;
        for (int slj = 0; slj < 64; slj++) a += eS[m * 64 + slj] * Vt[slj * 65 + d];
        accn[ii] += a;
      }
    }
  }
  if (tid < 10) denS[tid] = myden;
  __syncthreads();
#pragma unroll
  for (int ii = 0; ii < 3; ii++) {
    int idx = tid + ii * 256;
    if (idx < 640) {
      int m = idx >> 6;
      kvout[(size_t)bh * 640 + idx] = accn[ii] / denS[m];
    }
  }
}

// ---------------- attn row = k1inv row @ kv, then LayerNorm(g1,be1) -> bf16 ----------------
__global__ __launch_bounds__(256) void attn_ln1(const float* __restrict__ k1inv, const float* __restrict__ kvg,
                                                const float* __restrict__ g1, const float* __restrict__ be1,
                                                short* __restrict__ h1) {
  int blk = blockIdx.x;
  int b = blk / SS;
  __shared__ float pS[160];
  __shared__ float red[8];
  for (int i = threadIdx.x; i < 160; i += 256) pS[i] = k1inv[(size_t)blk * 160 + i];
  __syncthreads();
  float vals[4], s1 = 0.f, s2 = 0.f;
#pragma unroll
  for (int i = 0; i < 4; i++) {
    int e = threadIdx.x + i * 256;
    int h = e >> 6, d = e & 63;
    const float* kvp = &kvg[((size_t)(b * HH + h) * MLM) * HDIM + d];
    const float* pp = &pS[h * 10];
    float a = 0.f;
#pragma unroll
    for (int m = 0; m < 10; m++) a += pp[m] * kvp[m * 64];
    vals[i] = a; s1 += a; s2 += a * a;
  }
#pragma unroll
  for (int off = 32; off; off >>= 1) { s1 += __shfl_down(s1, off); s2 += __shfl_down(s2, off); }
  int wv = threadIdx.x >> 6;
  if ((threadIdx.x & 63) == 0) { red[wv] = s1; red[4 + wv] = s2; }
  __syncthreads();
  float t1 = red[0] + red[1] + red[2] + red[3];
  float t2 = red[4] + red[5] + red[6] + red[7];
  float mean = t1 * (1.f / 1024.f);
  float var = t2 * (1.f / 1024.f) - mean * mean;
  float ninv = rsqrtf(var + 1e-5f);
#pragma unroll
  for (int i = 0; i < 4; i++) {
    int e = threadIdx.x + i * 256;
    h1[(size_t)blk * EE + e] = f2bf((vals[i] - mean) * ninv * g1[e] + be1[e]);
  }
}

// ---------------- LayerNorm(g2,be2) on f32 rows -> bf16 ----------------
__global__ __launch_bounds__(256) void ln2_kernel(const float* __restrict__ h2, const float* __restrict__ g2,
                                                  const float* __restrict__ be2, short* __restrict__ h3) {
  int blk = blockIdx.x;
  __shared__ float red[8];
  float vals[4], s1 = 0.f, s2 = 0.f;
#pragma unroll
  for (int i = 0; i < 4; i++) {
    int e = threadIdx.x + i * 256;
    float a = h2[(size_t)blk * EE + e];
    vals[i] = a; s1 += a; s2 += a * a;
  }
#pragma unroll
  for (int off = 32; off; off >>= 1) { s1 += __shfl_down(s1, off); s2 += __shfl_down(s2, off); }
  int wv = threadIdx.x >> 6;
  if ((threadIdx.x & 63) == 0) { red[wv] = s1; red[4 + wv] = s2; }
  __syncthreads();
  float t1 = red[0] + red[1] + red[2] + red[3];
  float t2 = red[4] + red[5] + red[6] + red[7];
  float mean = t1 * (1.f / 1024.f);
  float var = t2 * (1.f / 1024.f) - mean * mean;
  float ninv = rsqrtf(var + 1e-5f);
#pragma unroll
  for (int i = 0; i < 4; i++) {
    int e = threadIdx.x + i * 256;
    h3[(size_t)blk * EE + e] = f2bf((vals[i] - mean) * ninv * g2[e] + be2[e]);
  }
}

// ---------------- h3 (B,S,E) bf16 -> out (B,E,S) f32 ----------------
__global__ __launch_bounds__(256) void transpose_out(const short* __restrict__ h3, float* __restrict__ outp) {
  __shared__ short tile[64 * 65];
  int b = blockIdx.z;
  int e0 = blockIdx.y * 64;
  int s0 = blockIdx.x * 64;
  int tx = threadIdx.x & 63;
  int ty = threadIdx.x >> 6;
#pragma unroll
  for (int i = 0; i < 16; i++) {
    int r = ty + i * 4;
    int s = s0 + r;
    if (s < SS) tile[r * 65 + tx] = h3[((size_t)b * SS + s) * EE + e0 + tx];
  }
  __syncthreads();
#pragma unroll
  for (int i = 0; i < 16; i++) {
    int c = ty + i * 4;
    int s = s0 + tx;
    if (s < SS) outp[((size_t)b * EE + e0 + c) * SS + s] = bf2f(tile[tx * 65 + c]);
  }
}

// ---------------- workspace layout (tight aliasing, ~198 MB total) ----------------
#define ALIGN_UP(x) (((x) + 255) & ~(size_t)255)
static const size_t SZ_XB   = (size_t)BB * SS * EE * 2;          // 32.77 MB (slot A: xb -> h1)
static const size_t SZ_WCAT = (size_t)QKV_N * EE * 2;            // 6.29 MB  (slot D)
static const size_t SZ_W1B  = (size_t)MLPD * EE * 2;             // 8.39 MB
static const size_t SZ_W2B  = (size_t)EE * MLPD * 2;             // 8.39 MB
static const size_t SZ_QKV  = (size_t)BB * SS * QKV_N * 2;       // 98.3 MB
static const int    CH0_NB  = 63, CH1_NB = 62;                   // 8064 + 7936 = 16000 rows
static const size_t SZ_MID0 = (size_t)CH0_NB * 128 * MLPD * 2;   // 66.06 MB
static const size_t SZ_H2_0 = (size_t)CH0_NB * 128 * EE * 4;     // 33.03 MB
static const size_t SZ_SLOTB = (SZ_QKV > ALIGN_UP(SZ_MID0) + SZ_H2_0)
                               ? SZ_QKV : (ALIGN_UP(SZ_MID0) + SZ_H2_0); // 99.1 MB
static const size_t SZ_QL   = (size_t)BB * HH * MLM * HDIM * 4;  // 327 KB
static const size_t SZ_K2   = (size_t)BB * HH * 100 * 4;
static const size_t SZ_ST   = 512;
static const size_t SZ_K1I  = (size_t)BB * SS * HH * MLM * 4;    // 10.24 MB

extern "C" void kernel_launch(void* const* d_in, const int* in_sizes, int n_in,
                              void* d_out, int out_size, void* d_ws, size_t ws_size,
                              hipStream_t stream) {
  // Inputs f32; output f32.
  const float* X   = (const float*)d_in[0];
  const float* Wq  = (const float*)d_in[1];
  const float* bq  = (const float*)d_in[2];
  const float* Wk  = (const float*)d_in[3];
  const float* bk  = (const float*)d_in[4];
  const float* Wv  = (const float*)d_in[5];
  const float* bv  = (const float*)d_in[6];
  const float* g1  = (const float*)d_in[7];
  const float* be1 = (const float*)d_in[8];
  const float* W1  = (const float*)d_in[9];
  const float* b1  = (const float*)d_in[10];
  const float* W2  = (const float*)d_in[11];
  const float* b2  = (const float*)d_in[12];
  const float* g2  = (const float*)d_in[13];
  const float* be2 = (const float*)d_in[14];

  char* ws = (char*)d_ws;
  size_t off = 0;
  char* slotA = ws + off; off += ALIGN_UP(SZ_XB);     // xb -> h1
  char* slotB = ws + off; off += ALIGN_UP(SZ_SLOTB);  // qkv -> mid+h2 chunks
  char* slotC = ws + off; off += ALIGN_UP(SZ_XB);     // h3
  char* slotD = ws + off; off += ALIGN_UP(SZ_WCAT);   // Wcat -> small f32 bufs
  short* W1b = (short*)(ws + off); off += ALIGN_UP(SZ_W1B);
  short* W2b = (short*)(ws + off); off += ALIGN_UP(SZ_W2B);
  float* k1ib = (float*)(ws + off); off += ALIGN_UP(SZ_K1I);

  short* xb   = (short*)slotA;
  short* h1   = (short*)slotA;
  short* qkv  = (short*)slotB;
  short* mid  = (short*)slotB;
  float* h2c  = (float*)(slotB + ALIGN_UP(SZ_MID0));
  short* h3   = (short*)slotC;
  short* Wcat = (short*)slotD;
  size_t doff = 0;
  float* Qlm  = (float*)(slotD + doff); doff += ALIGN_UP(SZ_QL);
  float* Klm  = (float*)(slotD + doff); doff += ALIGN_UP(SZ_QL);
  float* k2b  = (float*)(slotD + doff); doff += ALIGN_UP(SZ_K2);
  float* cmaxb= (float*)(slotD + doff); doff += ALIGN_UP(SZ_ST);
  float* rmaxb= (float*)(slotD + doff); doff += ALIGN_UP(SZ_ST);
  float* invb = (float*)(slotD + doff); doff += ALIGN_UP(SZ_K2);
  float* kvb  = (float*)(slotD + doff); doff += ALIGN_UP(SZ_QL);
  (void)ws_size; (void)in_sizes; (void)n_in; (void)out_size;

  // 1. transpose/cast X
  transpose_x<<<dim3(63, 32, BB), dim3(32, 8), 0, stream>>>(X, xb);
  // 2. weight casts f32 -> bf16
  cast_f2b<<<2048, 256, 0, stream>>>(Wq, Wcat,             EE * EE);
  cast_f2b<<<2048, 256, 0, stream>>>(Wk, Wcat + EE * EE,   EE * EE);
  cast_f2b<<<2048, 256, 0, stream>>>(Wv, Wcat + 2*EE*EE,   EE * EE);
  cast_f2b<<<4096, 256, 0, stream>>>(W1, W1b, MLPD * EE);
  cast_f2b<<<4096, 256, 0, stream>>>(W2, W2b, EE * MLPD);
  // 3. QKV projection GEMM (M=16000, N=3072, K=1024); 1-D grid, XCD remap inside
  gemm_bt<<<125 * 24, 256, 0, stream>>>(xb, Wcat, qkv, EE, QKV_N, 0, bq, bk, bv);
  // 4. landmarks
  landmarks<<<dim3(BB * HH * MLM, 2), 64, 0, stream>>>(qkv, Qlm, Klm);
  // 5. k2 + stats
  k2stats<<<BB * HH, 128, 0, stream>>>(Qlm, Klm, k2b, cmaxb, rmaxb);
  // 6. iterative inverse
  invk<<<BB * HH, 128, 0, stream>>>(k2b, cmaxb, rmaxb, invb);
  // 7. k1 @ inv
  k1inv_kernel<<<dim3(125, BB), 256, 0, stream>>>(qkv, Klm, invb, k1ib);
  // 8. k3 @ V
  k3v_kernel<<<BB * HH, 256, 0, stream>>>(qkv, Qlm, kvb);
  // 9. attn + LN1
  attn_ln1<<<BB * SS, 256, 0, stream>>>(k1ib, kvb, g1, be1, h1);
  // 10-12. MLP + LN2, in two row-chunks (qkv dead now)
  int row0 = 0;
  for (int c = 0; c < 2; c++) {
    int nb = (c == 0) ? CH0_NB : CH1_NB;
    int rows = nb * 128;
    gemm_bt<<<nb * 32, 256, 0, stream>>>(h1 + (size_t)row0 * EE, W1b, mid, EE, MLPD, 1, b1, nullptr, nullptr);
    gemm_bt<<<nb * 8,  256, 0, stream>>>(mid, W2b, h2c, MLPD, EE, 2, b2, nullptr, nullptr);
    ln2_kernel<<<rows, 256, 0, stream>>>(h2c, g2, be2, h3 + (size_t)row0 * EE);
    row0 += rows;
  }
  // 13. transpose to (B,E,S) f32
  transpose_out<<<dim3(32, 16, BB), 256, 0, stream>>>(h3, (float*)d_out);
}